// Round 5
// baseline (307.832 us; speedup 1.0000x reference)
//
#include <hip/hip_runtime.h>

// ---------------------------------------------------------------------------
// GenView, round 14.
//
// Algebra (verified R1-R8): per-row softmax cancels emb[row]·w1 and biases.
//   q[n]    = feat[n] . (W @ w2)
//   t[n]    = exp( sum_{e:row=n} v[e]*q[col[e]] )
//   invS[n] = 1 / sum_{e:row=n} t[col[e]]
//   out[e]  = vori[e] + t[col[e]] * invS[row[e]]
//
// History: R9 = 207.8 us (5 dispatches, static sort||gemv, 1038 blocks).
// R11 cooperative mega: grid.sync ~60us each -> dead end. R12 per-block
// sort->gemv serialization: 216.5 (lost overlap + cnt false sharing).
// R13 k_finish edge-scatter fusion: 214.7 (800K scattered 4B out-writes
// ~= 50MB effective vs k_out's 3.2MB sequential). R14 = R9 backend exactly,
// k_fused restructured:
//  - 512 blocks = exactly 2/CU, ONE occupancy round (R9 had 2 rounds + a
//    14-block straggler round).
//  - 256 sort blocks || 256 gemv blocks, but gemv rows come from a global
//    ATOMIC DISPENSER (16 rows/wave-grab, consecutive rows = 32KB
//    sequential streams); sort blocks JOIN the gemv pool when done. No
//    static tail, no idle CUs.
//  - cnt[] padded CPAD=16 u32 (64B line per counter) -> reservation RMWs
//    don't false-share (R12 diagnosis).
// Bucket sort: row>>7 -> 391 buckets, CAP=3072 (mean fill 2046, 22 sigma),
// LDS hist -> global reserve -> scatter. Backend kernels verified R9.
// ---------------------------------------------------------------------------

typedef unsigned int u32;

#define RPB     128          // rows per bucket
#define CAP     3072         // record slots per bucket
#define NB_MAX  512          // max buckets (N <= 65536)
#define CPAD    16           // cnt[] stride in u32 (64B line per counter)
#define SB      256          // sort blocks (first SB of the 512)
#define FG      512          // fused grid total (2 blocks/CU, one round)
#define GCHUNK  16           // gemv rows per wave grab

// ---- u2[f] = sum_h W[f,h]*mw[H+h]; block 0 also zeros cnt[]+disp ----
__global__ void k_prep(const float* __restrict__ W, const float* __restrict__ mw,
                       float* __restrict__ u2, u32* __restrict__ cnt,
                       int F, int H, int nz) {
  if (blockIdx.x == 0)
    for (int s = threadIdx.x; s < nz; s += blockDim.x) cnt[s] = 0;
  int f = blockIdx.x * blockDim.x + threadIdx.x;
  if (f >= F) return;
  const float4* wr = (const float4*)(W + (size_t)f * H);
  const float4* mv = (const float4*)(mw + H);
  float s = 0.f;
  for (int i = 0; i < H / 4; ++i) {
    float4 a = wr[i], b = mv[i];
    s = fmaf(a.x, b.x, fmaf(a.y, b.y, fmaf(a.z, b.z, fmaf(a.w, b.w, s))));
  }
  u2[f] = s;
}

// ---- fused: blocks [0,SB) sort then join gemv; blocks [SB,FG) gemv ----
// gemv rows from atomic dispenser `disp` (16 consecutive rows per grab).
template <int F>
__global__ void __launch_bounds__(1024)
k_fused(const int* __restrict__ row, const int* __restrict__ col,
        const float* __restrict__ v, const float* __restrict__ feat,
        const float* __restrict__ u2, float* __restrict__ q,
        u32* __restrict__ cnt, u32* __restrict__ disp,
        uint2* __restrict__ rec8, int E, int N, int nb) {
  __shared__ u32 h[NB_MAX];
  __shared__ u32 start[NB_MAX];
  const int tid  = threadIdx.x;
  const int lane = tid & 63;

  if (blockIdx.x < SB) {
    // ---------------- sort path ----------------
    const int chunk = (E + SB - 1) / SB;
    for (int s = tid; s < nb; s += 1024) h[s] = 0;
    __syncthreads();
    const int lo = blockIdx.x * chunk;
    const int hi = min(E, lo + chunk);
    for (int e = lo + tid; e < hi; e += 1024)
      atomicAdd(&h[row[e] >> 7], 1u);
    __syncthreads();
    for (int s = tid; s < nb; s += 1024) {
      u32 c = h[s];
      start[s] = c ? atomicAdd(&cnt[(size_t)s * CPAD], c) : 0u; // 1 line/ctr
      h[s] = 0u;                                                // local rank
    }
    __syncthreads();
    for (int e = lo + tid; e < hi; e += 1024) {
      int r = row[e];
      int b = r >> 7;
      u32 rank = atomicAdd(&h[b], 1u);
      u32 off  = min(start[b] + rank, (u32)(CAP - 1));  // memory-safety clamp
      rec8[(size_t)b * CAP + off] =
          make_uint2(((u32)col[e] << 7) | (u32)(r & 127),
                     __float_as_uint(v[e]));
    }
    // fall through: join the gemv pool
  }

  // ---------------- gemv: dynamic dispenser, all blocks ----------------
  {
    const float4 ua = *(const float4*)(u2 + lane * 8);
    const float4 ub = *(const float4*)(u2 + lane * 8 + 4);
    for (;;) {
      u32 base = 0;
      if (lane == 0) base = atomicAdd(disp, (u32)GCHUNK);
      base = __shfl(base, 0);
      if (base >= (u32)N) break;
      const u32 end = min(base + (u32)GCHUNK, (u32)N);
      for (u32 r = base; r < end; ++r) {
        const float* fr = feat + (size_t)r * F + lane * 8;
        float4 a = *(const float4*)fr;
        float4 b = *(const float4*)(fr + 4);
        float s = fmaf(a.x, ua.x, fmaf(a.y, ua.y, fmaf(a.z, ua.z,
                  fmaf(a.w, ua.w, fmaf(b.x, ub.x, fmaf(b.y, ub.y,
                  fmaf(b.z, ub.z, b.w * ub.w)))))));
        s += __shfl_xor(s, 32);
        s += __shfl_xor(s, 16);
        s += __shfl_xor(s, 8);
        s += __shfl_xor(s, 4);
        s += __shfl_xor(s, 2);
        s += __shfl_xor(s, 1);
        if (lane == 0) q[r] = s;
      }
    }
  }
}

// ---- per-bucket: t[row] = exp( sum v * q[col] )  (verified R9 kernel) ----
__global__ void __launch_bounds__(1024)
k_sum_t(const uint2* __restrict__ rec8, const u32* __restrict__ cnt,
        const float* __restrict__ q, float* __restrict__ t) {
  __shared__ float acc[RPB];
  const int b = blockIdx.x;
  const int tid = threadIdx.x;
  if (tid < RPB) acc[tid] = 0.f;
  __syncthreads();
  const u32 lo = (u32)b * CAP;
  const u32 n  = min(cnt[(size_t)b * CPAD], (u32)CAP);
  for (u32 i = tid; i < n; i += blockDim.x) {
    uint2 rr = rec8[lo + i];
    atomicAdd(&acc[rr.x & 127], q[rr.x >> 7] * __uint_as_float(rr.y));
  }
  __syncthreads();
  if (tid < RPB) t[b * RPB + tid] = __expf(acc[tid]);
}

// ---- per-bucket: invS[row] = 1 / sum t[col]  (verified R9 kernel) ----
__global__ void __launch_bounds__(1024)
k_sum_invS(const uint2* __restrict__ rec8, const u32* __restrict__ cnt,
           const float* __restrict__ t, float* __restrict__ invS) {
  __shared__ float acc[RPB];
  const int b = blockIdx.x;
  const int tid = threadIdx.x;
  if (tid < RPB) acc[tid] = 0.f;
  __syncthreads();
  const u32 lo = (u32)b * CAP;
  const u32 n  = min(cnt[(size_t)b * CPAD], (u32)CAP);
  for (u32 i = tid; i < n; i += blockDim.x) {
    uint2 rr = rec8[lo + i];
    atomicAdd(&acc[rr.x & 127], t[rr.x >> 7]);
  }
  __syncthreads();
  if (tid < RPB) invS[b * RPB + tid] = 1.0f / acc[tid]; // empty rows never read
}

// ---- linear, 4 edges/thread (verified R9 kernel) ----
__global__ void k_out(const int* __restrict__ row, const int* __restrict__ col,
                      const float* __restrict__ vori, const float* __restrict__ t,
                      const float* __restrict__ invS, float* __restrict__ out,
                      int E) {
  int e4 = blockIdx.x * blockDim.x + threadIdx.x;
  int e  = e4 * 4;
  if (e + 3 < E) {
    int4   r4 = *(const int4*)(row + e);
    int4   c4 = *(const int4*)(col + e);
    float4 v4 = *(const float4*)(vori + e);
    float4 o;
    o.x = v4.x + t[c4.x] * invS[r4.x];
    o.y = v4.y + t[c4.y] * invS[r4.y];
    o.z = v4.z + t[c4.z] * invS[r4.z];
    o.w = v4.w + t[c4.w] * invS[r4.w];
    *(float4*)(out + e) = o;
  } else {
    for (; e < E; ++e)
      out[e] = vori[e] + t[col[e]] * invS[row[e]];
  }
}

// ---- last-resort fallback (ws too small / shape mismatch): global-atomic ----
__global__ void k_gemv_fb(const float* __restrict__ feat, const float* __restrict__ u2,
                          float* __restrict__ q, int N, int F) {
  const int lane = threadIdx.x & 63;
  const int wave = (blockIdx.x * blockDim.x + threadIdx.x) >> 6;
  if (wave >= N) return;
  const float* fr = feat + (size_t)wave * F;
  float a = 0.f;
  for (int i = lane; i < F; i += 64) a = fmaf(fr[i], u2[i], a);
  for (int off = 32; off; off >>= 1) a += __shfl_xor(a, off);
  if (lane == 0) q[wave] = a;
}
__global__ void k_scatter_B_at(const int* __restrict__ row, const int* __restrict__ col,
                               const float* __restrict__ v, const float* __restrict__ q,
                               float* __restrict__ B, int E) {
  int e = blockIdx.x * blockDim.x + threadIdx.x;
  if (e >= E) return;
  atomicAdd(&B[row[e]], v[e] * q[col[e]]);
}
__global__ void k_node_t(const float* __restrict__ B, float* __restrict__ t, int N) {
  int n = blockIdx.x * blockDim.x + threadIdx.x;
  if (n < N) t[n] = __expf(B[n]);
}
__global__ void k_scatter_S_at(const int* __restrict__ row, const int* __restrict__ col,
                               const float* __restrict__ t, float* __restrict__ S, int E) {
  int e = blockIdx.x * blockDim.x + threadIdx.x;
  if (e >= E) return;
  atomicAdd(&S[row[e]], t[col[e]]);
}
__global__ void k_out_div(const int* __restrict__ row, const int* __restrict__ col,
                          const float* __restrict__ vori, const float* __restrict__ t,
                          const float* __restrict__ S, float* __restrict__ out, int E) {
  int e = blockIdx.x * blockDim.x + threadIdx.x;
  if (e >= E) return;
  out[e] = vori[e] + t[col[e]] / S[row[e]];
}

extern "C" void kernel_launch(void* const* d_in, const int* in_sizes, int n_in,
                              void* d_out, int out_size, void* d_ws, size_t ws_size,
                              hipStream_t stream) {
  const float* vori = (const float*)d_in[0];
  const float* feat = (const float*)d_in[1];
  const int*   vind = (const int*)d_in[2];
  const float* W    = (const float*)d_in[4];
  const float* mw   = (const float*)d_in[6];

  const int E = in_sizes[0];
  const int H = in_sizes[6] / 2;        // 128
  const int F = in_sizes[4] / H;        // 512
  const int N = in_sizes[1] / F;        // 50000

  const int* row = vind;
  const int* col = vind + E;

  const int nb   = (N + RPB - 1) / RPB; // 391
  const int npad = nb * RPB;

  // ---- workspace:
  //   u2(F) q(N) t(npad) invS(npad) | cnt(nb*CPAD u32) disp(16 u32) |
  //   rec8(nb*CAP uint2)
  float* ws   = (float*)d_ws;
  float* u2   = ws;
  float* q    = u2 + F;
  float* t    = q + N;
  float* invS = t + npad;
  u32*   cnt  = (u32*)(invS + npad);
  u32*   disp = cnt + (size_t)nb * CPAD;   // own 64B line
  size_t hdr  = (size_t)((char*)(disp + 16) - (char*)d_ws);
  hdr = (hdr + 63) & ~(size_t)63;
  uint2* rec8 = (uint2*)((char*)d_ws + hdr);
  size_t need = hdr + (size_t)nb * CAP * sizeof(uint2);

  k_prep<<<(F + 255) / 256, 256, 0, stream>>>(W, mw, u2, cnt, F, H,
                                              nb * CPAD + 16);

  if (ws_size >= need && F == 512 && H % 4 == 0 && nb <= NB_MAX) {
    // ---- R14: 5 dispatches, dynamic-balanced fused front ----
    k_fused<512><<<FG, 1024, 0, stream>>>(row, col, vori, feat, u2, q,
                                          cnt, disp, rec8, E, N, nb);
    k_sum_t<<<nb, 1024, 0, stream>>>(rec8, cnt, q, t);
    k_sum_invS<<<nb, 1024, 0, stream>>>(rec8, cnt, t, invS);
    const int e4 = (E + 3) / 4;
    k_out<<<(e4 + 255) / 256, 256, 0, stream>>>(row, col, vori, t, invS,
                                                (float*)d_out, E);
  } else {
    const int eb  = (E + 255) / 256;
    const int nbk = (N + 255) / 256;
    float* S = invS;
    k_gemv_fb<<<(N * 64 + 255) / 256, 256, 0, stream>>>(feat, u2, q, N, F);
    hipMemsetAsync((void*)S, 0, sizeof(float) * (size_t)npad, stream);
    k_scatter_B_at<<<eb, 256, 0, stream>>>(row, col, vori, q, S, E);
    k_node_t<<<nbk, 256, 0, stream>>>(S, t, N);
    hipMemsetAsync((void*)S, 0, sizeof(float) * (size_t)npad, stream);
    k_scatter_S_at<<<eb, 256, 0, stream>>>(row, col, t, S, E);
    k_out_div<<<eb, 256, 0, stream>>>(row, col, vori, t, S, (float*)d_out, E);
  }
}

// Round 6
// 211.227 us; speedup vs baseline: 1.4573x; 1.4573x over previous
//
#include <hip/hip_runtime.h>

// ---------------------------------------------------------------------------
// GenView, round 15.
//
// Algebra (verified R1-R8): per-row softmax cancels emb[row]·w1 and biases.
//   q[n]    = feat[n] . (W @ w2)
//   t[n]    = exp( sum_{e:row=n} v[e]*q[col[e]] )
//   invS[n] = 1 / sum_{e:row=n} t[col[e]]
//   out[e]  = vori[e] + t[col[e]] * invS[row[e]]
//
// Same-line device-atomic serialization theory (calibrated R12/R14):
// device-scope RMWs to one 64B line serialize at ~7-13ns/op across XCDs.
//   R14 dispenser: 11.3K ops/1 line = 147us (measured).
//   R12 reserve: dense cnt[], 16 ctrs/line x 512 blocks = 8.2K ops/line
//     = ~57us (measured 62us, VALUBusy 4%).
//   R9 baseline: 16 ctrs/line x 256 blocks = 4.1K ops/line = ~29us hidden
//     inside k_fused.
// R15 = R9's verified 207.8us kernel EXACTLY, with one change: cnt[] strided
// CPAD=16 u32 -> one counter per 64B line -> reserve atomics parallel across
// 391 lines (256 ops/line ~ 2us). No recE, no k_finish, no dispenser
// (all measured regressions, reverted).
// Bucket sort: row>>7 -> 391 buckets, CAP=3072 (mean fill 2046, 22 sigma),
// LDS hist -> global reserve -> scatter. k_out: 4 edges/thread, vectorized.
// ---------------------------------------------------------------------------

typedef unsigned int u32;

#define RPB     128          // rows per bucket
#define CAP     3072         // record slots per bucket
#define NB_MAX  512          // max buckets (N <= 65536)
#define CPAD    16           // cnt[] stride in u32 (one 64B line per counter)
#define SB      256          // sort blocks (first SB blocks of k_fused)
#define GB      782          // gemv blocks (16 waves each -> 12512 waves)

// ---- u2[f] = sum_h W[f,h]*mw[H+h]; block 0 also zeros cnt[] ----
__global__ void k_prep(const float* __restrict__ W, const float* __restrict__ mw,
                       float* __restrict__ u2, u32* __restrict__ cnt,
                       int F, int H, int nz) {
  if (blockIdx.x == 0)
    for (int s = threadIdx.x; s < nz; s += blockDim.x) cnt[s] = 0;
  int f = blockIdx.x * blockDim.x + threadIdx.x;
  if (f >= F) return;
  const float4* wr = (const float4*)(W + (size_t)f * H);
  const float4* mv = (const float4*)(mw + H);
  float s = 0.f;
  for (int i = 0; i < H / 4; ++i) {
    float4 a = wr[i], b = mv[i];
    s = fmaf(a.x, b.x, fmaf(a.y, b.y, fmaf(a.z, b.z, fmaf(a.w, b.w, s))));
  }
  u2[f] = s;
}

// ---- fused: blocks [0,SB) bucket-sort edges; blocks [SB,SB+GB) gemv ----
// sort: rec8[slot] = (col<<7 | row&127, bits(v)); LDS hist -> global
//       reserve (padded counters) -> scatter.
// gemv: 64 lanes/row, q[r] = feat[r].u2 (u-fragment = 2 float4 in VGPRs).
template <int F>
__global__ void __launch_bounds__(1024)
k_fused(const int* __restrict__ row, const int* __restrict__ col,
        const float* __restrict__ v, const float* __restrict__ feat,
        const float* __restrict__ u2, float* __restrict__ q,
        u32* __restrict__ cnt, uint2* __restrict__ rec8,
        int E, int N, int nb) {
  __shared__ u32 h[NB_MAX];
  __shared__ u32 start[NB_MAX];
  const int tid = threadIdx.x;

  if (blockIdx.x < SB) {
    // ---------------- sort path ----------------
    const int chunk = (E + SB - 1) / SB;
    for (int s = tid; s < nb; s += blockDim.x) h[s] = 0;
    __syncthreads();
    const int lo = blockIdx.x * chunk;
    const int hi = min(E, lo + chunk);
    for (int e = lo + tid; e < hi; e += blockDim.x)
      atomicAdd(&h[row[e] >> 7], 1u);
    __syncthreads();
    for (int s = tid; s < nb; s += blockDim.x) {
      u32 c = h[s];
      start[s] = c ? atomicAdd(&cnt[(size_t)s * CPAD], c) : 0u; // 1 line/ctr
      h[s] = 0u;                                                // local rank
    }
    __syncthreads();
    for (int e = lo + tid; e < hi; e += blockDim.x) {
      int r = row[e];
      int b = r >> 7;
      u32 rank = atomicAdd(&h[b], 1u);
      u32 off  = min(start[b] + rank, (u32)CAP - 1);  // memory-safety clamp
      rec8[(size_t)b * CAP + off] =
          make_uint2(((u32)col[e] << 7) | (u32)(r & 127),
                     __float_as_uint(v[e]));
    }
  } else {
    // ---------------- gemv path ----------------
    const int lane = tid & 63;
    const float4 ua = *(const float4*)(u2 + lane * 8);
    const float4 ub = *(const float4*)(u2 + lane * 8 + 4);
    const int wid = (blockIdx.x - SB) * (1024 >> 6) + (tid >> 6);
    const int nw  = GB * (1024 >> 6);
    for (int r = wid; r < N; r += nw) {
      const float* fr = feat + (size_t)r * F + lane * 8;
      float4 a = *(const float4*)fr;
      float4 b = *(const float4*)(fr + 4);
      float s = fmaf(a.x, ua.x, fmaf(a.y, ua.y, fmaf(a.z, ua.z,
                fmaf(a.w, ua.w, fmaf(b.x, ub.x, fmaf(b.y, ub.y,
                fmaf(b.z, ub.z, b.w * ub.w)))))));
      s += __shfl_xor(s, 32);
      s += __shfl_xor(s, 16);
      s += __shfl_xor(s, 8);
      s += __shfl_xor(s, 4);
      s += __shfl_xor(s, 2);
      s += __shfl_xor(s, 1);
      if (lane == 0) q[r] = s;
    }
  }
}

// ---- per-bucket: t[row] = exp( sum v * q[col] ) ----
__global__ void __launch_bounds__(1024)
k_sum_t(const uint2* __restrict__ rec8, const u32* __restrict__ cnt,
        const float* __restrict__ q, float* __restrict__ t) {
  __shared__ float acc[RPB];
  const int b = blockIdx.x;
  const int tid = threadIdx.x;
  if (tid < RPB) acc[tid] = 0.f;
  __syncthreads();
  const u32 lo = (u32)b * CAP;
  const u32 n  = min(cnt[(size_t)b * CPAD], (u32)CAP);
  for (u32 i = tid; i < n; i += blockDim.x) {
    uint2 rr = rec8[lo + i];
    atomicAdd(&acc[rr.x & 127], q[rr.x >> 7] * __uint_as_float(rr.y));
  }
  __syncthreads();
  if (tid < RPB) t[b * RPB + tid] = __expf(acc[tid]);
}

// ---- per-bucket: invS[row] = 1 / sum t[col] ----
__global__ void __launch_bounds__(1024)
k_sum_invS(const uint2* __restrict__ rec8, const u32* __restrict__ cnt,
           const float* __restrict__ t, float* __restrict__ invS) {
  __shared__ float acc[RPB];
  const int b = blockIdx.x;
  const int tid = threadIdx.x;
  if (tid < RPB) acc[tid] = 0.f;
  __syncthreads();
  const u32 lo = (u32)b * CAP;
  const u32 n  = min(cnt[(size_t)b * CPAD], (u32)CAP);
  for (u32 i = tid; i < n; i += blockDim.x) {
    uint2 rr = rec8[lo + i];
    atomicAdd(&acc[rr.x & 127], t[rr.x >> 7]);
  }
  __syncthreads();
  if (tid < RPB) invS[b * RPB + tid] = 1.0f / acc[tid]; // empty rows never read
}

// ---- linear, 4 edges/thread: out[e] = vori[e] + t[col[e]] * invS[row[e]] ----
__global__ void k_out(const int* __restrict__ row, const int* __restrict__ col,
                      const float* __restrict__ vori, const float* __restrict__ t,
                      const float* __restrict__ invS, float* __restrict__ out,
                      int E) {
  int e4 = blockIdx.x * blockDim.x + threadIdx.x;
  int e  = e4 * 4;
  if (e + 3 < E) {
    int4   r4 = *(const int4*)(row + e);
    int4   c4 = *(const int4*)(col + e);
    float4 v4 = *(const float4*)(vori + e);
    float4 o;
    o.x = v4.x + t[c4.x] * invS[r4.x];
    o.y = v4.y + t[c4.y] * invS[r4.y];
    o.z = v4.z + t[c4.z] * invS[r4.z];
    o.w = v4.w + t[c4.w] * invS[r4.w];
    *(float4*)(out + e) = o;
  } else {
    for (; e < E; ++e)
      out[e] = vori[e] + t[col[e]] * invS[row[e]];
  }
}

// ---- fallback path (ws too small / shape mismatch): global-atomic ----
__global__ void k_gemv_fb(const float* __restrict__ feat, const float* __restrict__ u2,
                          float* __restrict__ q, int N, int F) {
  const int lane = threadIdx.x & 63;
  const int wave = (blockIdx.x * blockDim.x + threadIdx.x) >> 6;
  if (wave >= N) return;
  const float* fr = feat + (size_t)wave * F;
  float a = 0.f;
  for (int i = lane; i < F; i += 64) a = fmaf(fr[i], u2[i], a);
  for (int off = 32; off; off >>= 1) a += __shfl_xor(a, off);
  if (lane == 0) q[wave] = a;
}
__global__ void k_scatter_B_at(const int* __restrict__ row, const int* __restrict__ col,
                               const float* __restrict__ v, const float* __restrict__ q,
                               float* __restrict__ B, int E) {
  int e = blockIdx.x * blockDim.x + threadIdx.x;
  if (e >= E) return;
  atomicAdd(&B[row[e]], v[e] * q[col[e]]);
}
__global__ void k_node_t(const float* __restrict__ B, float* __restrict__ t, int N) {
  int n = blockIdx.x * blockDim.x + threadIdx.x;
  if (n < N) t[n] = __expf(B[n]);
}
__global__ void k_scatter_S_at(const int* __restrict__ row, const int* __restrict__ col,
                               const float* __restrict__ t, float* __restrict__ S, int E) {
  int e = blockIdx.x * blockDim.x + threadIdx.x;
  if (e >= E) return;
  atomicAdd(&S[row[e]], t[col[e]]);
}
__global__ void k_out_div(const int* __restrict__ row, const int* __restrict__ col,
                          const float* __restrict__ vori, const float* __restrict__ t,
                          const float* __restrict__ S, float* __restrict__ out, int E) {
  int e = blockIdx.x * blockDim.x + threadIdx.x;
  if (e >= E) return;
  out[e] = vori[e] + t[col[e]] / S[row[e]];
}

extern "C" void kernel_launch(void* const* d_in, const int* in_sizes, int n_in,
                              void* d_out, int out_size, void* d_ws, size_t ws_size,
                              hipStream_t stream) {
  const float* vori = (const float*)d_in[0];
  const float* feat = (const float*)d_in[1];
  const int*   vind = (const int*)d_in[2];
  const float* W    = (const float*)d_in[4];
  const float* mw   = (const float*)d_in[6];

  const int E = in_sizes[0];
  const int H = in_sizes[6] / 2;        // 128
  const int F = in_sizes[4] / H;        // 512
  const int N = in_sizes[1] / F;        // 50000

  const int* row = vind;
  const int* col = vind + E;

  const int nb   = (N + RPB - 1) / RPB; // 391
  const int npad = nb * RPB;

  // ---- workspace: u2(F) q(N) t(npad) invS(npad) | cnt(nb*CPAD u32) |
  //      rec8(nb*CAP uint2)
  float* ws   = (float*)d_ws;
  float* u2   = ws;
  float* q    = u2 + F;
  float* t    = q + N;
  float* invS = t + npad;
  u32*   cnt  = (u32*)(invS + npad);
  size_t hdr  = (size_t)((char*)(cnt + (size_t)nb * CPAD) - (char*)d_ws);
  hdr = (hdr + 63) & ~(size_t)63;
  uint2* rec8 = (uint2*)((char*)d_ws + hdr);
  size_t need = hdr + (size_t)nb * CAP * sizeof(uint2);

  k_prep<<<(F + 255) / 256, 256, 0, stream>>>(W, mw, u2, cnt, F, H, nb * CPAD);

  if (ws_size >= need && F == 512 && H % 4 == 0 && nb <= NB_MAX) {
    k_fused<512><<<SB + GB, 1024, 0, stream>>>(row, col, vori, feat, u2, q,
                                               cnt, rec8, E, N, nb);
    k_sum_t<<<nb, 1024, 0, stream>>>(rec8, cnt, q, t);
    k_sum_invS<<<nb, 1024, 0, stream>>>(rec8, cnt, t, invS);
    const int e4 = (E + 3) / 4;
    k_out<<<(e4 + 255) / 256, 256, 0, stream>>>(row, col, vori, t, invS,
                                                (float*)d_out, E);
  } else {
    const int eb  = (E + 255) / 256;
    const int nbk = (N + 255) / 256;
    float* S = invS;
    k_gemv_fb<<<(N * 64 + 255) / 256, 256, 0, stream>>>(feat, u2, q, N, F);
    hipMemsetAsync((void*)S, 0, sizeof(float) * (size_t)npad, stream);
    k_scatter_B_at<<<eb, 256, 0, stream>>>(row, col, vori, q, S, E);
    k_node_t<<<nbk, 256, 0, stream>>>(S, t, N);
    hipMemsetAsync((void*)S, 0, sizeof(float) * (size_t)npad, stream);
    k_scatter_S_at<<<eb, 256, 0, stream>>>(row, col, t, S, E);
    k_out_div<<<eb, 256, 0, stream>>>(row, col, vori, t, S, (float*)d_out, E);
  }
}

// Round 8
// 208.085 us; speedup vs baseline: 1.4794x; 1.0151x over previous
//
#include <hip/hip_runtime.h>

// ---------------------------------------------------------------------------
// GenView, round 17 (= R16 resubmitted; R16's bench died to infra, not kernel).
//
// Algebra (verified R1-R8): per-row softmax cancels emb[row]·w1 and biases.
//   q[n]    = feat[n] . (W @ w2)
//   t[n]    = exp( sum_{e:row=n} v[e]*q[col[e]] )
//   invS[n] = 1 / sum_{e:row=n} t[col[e]]
//   out[e]  = vori[e] + t[col[e]] * invS[row[e]]
//
// Findings ledger:
//  R9  207.8us: SB=256 sort || GB=782 gemv, 5 dispatches.   <- best
//  R11 grid.sync ~60us/sync -> dead end.
//  R12 sort->gemv serialized per block: k_fused1r=62us, VALU 4%.
//  R13 recE+k_finish scatter fusion: +7us (scattered 4B out-writes).
//  R14 atomic row dispenser: 147us (same-line device RMW ~13ns serialized).
//  R15 CPAD padding alone: NEUTRAL (211.2 ~ noise) -> R9's reserve atomics
//      were never the bottleneck; sort cost is throughput work done by only
//      256 blocks (2 streaming passes + LDS hist/rank atomics + scattered
//      rec8 writes) racing a ~25us gemv.
//  R16 (this kernel): bench infra failed twice; no counters. Re-running.
// R16/R17: INTERLEAVED roles. SB=512 sort blocks (half-size chunks) at even
// blockIdx < 1024, gemv at odd + tail. First resident round is still
// 256 sort || 256 gemv (R9's mix), but sort wall-time halves; scheduler
// backfills with gemv blocks as sort retires. cnt[] stays CPAD-padded
// (512 reservers now). Backend kernels byte-identical to verified R9.
// Bucket sort: row>>7 -> 391 buckets, CAP=3072 (mean fill 2046, 22 sigma).
// ---------------------------------------------------------------------------

typedef unsigned int u32;

#define RPB     128          // rows per bucket
#define CAP     3072         // record slots per bucket
#define NB_MAX  512          // max buckets (N <= 65536)
#define CPAD    16           // cnt[] stride in u32 (one 64B line per counter)
#define SB      512          // sort blocks (even blockIdx < 2*SB)
#define GB      782          // gemv blocks (16 waves each -> 12512 waves)

// ---- u2[f] = sum_h W[f,h]*mw[H+h]; block 0 also zeros cnt[] ----
__global__ void k_prep(const float* __restrict__ W, const float* __restrict__ mw,
                       float* __restrict__ u2, u32* __restrict__ cnt,
                       int F, int H, int nz) {
  if (blockIdx.x == 0)
    for (int s = threadIdx.x; s < nz; s += blockDim.x) cnt[s] = 0;
  int f = blockIdx.x * blockDim.x + threadIdx.x;
  if (f >= F) return;
  const float4* wr = (const float4*)(W + (size_t)f * H);
  const float4* mv = (const float4*)(mw + H);
  float s = 0.f;
  for (int i = 0; i < H / 4; ++i) {
    float4 a = wr[i], b = mv[i];
    s = fmaf(a.x, b.x, fmaf(a.y, b.y, fmaf(a.z, b.z, fmaf(a.w, b.w, s))));
  }
  u2[f] = s;
}

// ---- fused, interleaved roles:
//   blockIdx < 2*SB:  even -> sort (id = blockIdx/2), odd -> gemv (id = blockIdx/2)
//   blockIdx >= 2*SB: gemv (id = blockIdx - SB)
// sort: rec8[slot] = (col<<7 | row&127, bits(v)); LDS hist -> global
//       reserve (padded counters) -> scatter.
// gemv: 64 lanes/row, q[r] = feat[r].u2 (u-fragment = 2 float4 in VGPRs).
template <int F>
__global__ void __launch_bounds__(1024)
k_fused(const int* __restrict__ row, const int* __restrict__ col,
        const float* __restrict__ v, const float* __restrict__ feat,
        const float* __restrict__ u2, float* __restrict__ q,
        u32* __restrict__ cnt, uint2* __restrict__ rec8,
        int E, int N, int nb) {
  __shared__ u32 h[NB_MAX];
  __shared__ u32 start[NB_MAX];
  const int tid = threadIdx.x;
  const int bid = blockIdx.x;

  const bool is_sort = (bid < 2 * SB) && ((bid & 1) == 0);

  if (is_sort) {
    // ---------------- sort path ----------------
    const int sid   = bid >> 1;                 // 0..SB-1
    const int chunk = (E + SB - 1) / SB;        // ~1563
    for (int s = tid; s < nb; s += blockDim.x) h[s] = 0;
    __syncthreads();
    const int lo = sid * chunk;
    const int hi = min(E, lo + chunk);
    for (int e = lo + tid; e < hi; e += blockDim.x)
      atomicAdd(&h[row[e] >> 7], 1u);
    __syncthreads();
    for (int s = tid; s < nb; s += blockDim.x) {
      u32 c = h[s];
      start[s] = c ? atomicAdd(&cnt[(size_t)s * CPAD], c) : 0u; // 1 line/ctr
      h[s] = 0u;                                                // local rank
    }
    __syncthreads();
    for (int e = lo + tid; e < hi; e += blockDim.x) {
      int r = row[e];
      int b = r >> 7;
      u32 rank = atomicAdd(&h[b], 1u);
      u32 off  = min(start[b] + rank, (u32)CAP - 1);  // memory-safety clamp
      rec8[(size_t)b * CAP + off] =
          make_uint2(((u32)col[e] << 7) | (u32)(r & 127),
                     __float_as_uint(v[e]));
    }
  } else {
    // ---------------- gemv path ----------------
    const int gid  = (bid < 2 * SB) ? (bid >> 1) : (bid - SB);  // 0..GB-1
    const int lane = tid & 63;
    const float4 ua = *(const float4*)(u2 + lane * 8);
    const float4 ub = *(const float4*)(u2 + lane * 8 + 4);
    const int wid = gid * (1024 >> 6) + (tid >> 6);
    const int nw  = GB * (1024 >> 6);
    for (int r = wid; r < N; r += nw) {
      const float* fr = feat + (size_t)r * F + lane * 8;
      float4 a = *(const float4*)fr;
      float4 b = *(const float4*)(fr + 4);
      float s = fmaf(a.x, ua.x, fmaf(a.y, ua.y, fmaf(a.z, ua.z,
                fmaf(a.w, ua.w, fmaf(b.x, ub.x, fmaf(b.y, ub.y,
                fmaf(b.z, ub.z, b.w * ub.w)))))));
      s += __shfl_xor(s, 32);
      s += __shfl_xor(s, 16);
      s += __shfl_xor(s, 8);
      s += __shfl_xor(s, 4);
      s += __shfl_xor(s, 2);
      s += __shfl_xor(s, 1);
      if (lane == 0) q[r] = s;
    }
  }
}

// ---- per-bucket: t[row] = exp( sum v * q[col] ) ----
__global__ void __launch_bounds__(1024)
k_sum_t(const uint2* __restrict__ rec8, const u32* __restrict__ cnt,
        const float* __restrict__ q, float* __restrict__ t) {
  __shared__ float acc[RPB];
  const int b = blockIdx.x;
  const int tid = threadIdx.x;
  if (tid < RPB) acc[tid] = 0.f;
  __syncthreads();
  const u32 lo = (u32)b * CAP;
  const u32 n  = min(cnt[(size_t)b * CPAD], (u32)CAP);
  for (u32 i = tid; i < n; i += blockDim.x) {
    uint2 rr = rec8[lo + i];
    atomicAdd(&acc[rr.x & 127], q[rr.x >> 7] * __uint_as_float(rr.y));
  }
  __syncthreads();
  if (tid < RPB) t[b * RPB + tid] = __expf(acc[tid]);
}

// ---- per-bucket: invS[row] = 1 / sum t[col] ----
__global__ void __launch_bounds__(1024)
k_sum_invS(const uint2* __restrict__ rec8, const u32* __restrict__ cnt,
           const float* __restrict__ t, float* __restrict__ invS) {
  __shared__ float acc[RPB];
  const int b = blockIdx.x;
  const int tid = threadIdx.x;
  if (tid < RPB) acc[tid] = 0.f;
  __syncthreads();
  const u32 lo = (u32)b * CAP;
  const u32 n  = min(cnt[(size_t)b * CPAD], (u32)CAP);
  for (u32 i = tid; i < n; i += blockDim.x) {
    uint2 rr = rec8[lo + i];
    atomicAdd(&acc[rr.x & 127], t[rr.x >> 7]);
  }
  __syncthreads();
  if (tid < RPB) invS[b * RPB + tid] = 1.0f / acc[tid]; // empty rows never read
}

// ---- linear, 4 edges/thread: out[e] = vori[e] + t[col[e]] * invS[row[e]] ----
__global__ void k_out(const int* __restrict__ row, const int* __restrict__ col,
                      const float* __restrict__ vori, const float* __restrict__ t,
                      const float* __restrict__ invS, float* __restrict__ out,
                      int E) {
  int e4 = blockIdx.x * blockDim.x + threadIdx.x;
  int e  = e4 * 4;
  if (e + 3 < E) {
    int4   r4 = *(const int4*)(row + e);
    int4   c4 = *(const int4*)(col + e);
    float4 v4 = *(const float4*)(vori + e);
    float4 o;
    o.x = v4.x + t[c4.x] * invS[r4.x];
    o.y = v4.y + t[c4.y] * invS[r4.y];
    o.z = v4.z + t[c4.z] * invS[r4.z];
    o.w = v4.w + t[c4.w] * invS[r4.w];
    *(float4*)(out + e) = o;
  } else {
    for (; e < E; ++e)
      out[e] = vori[e] + t[col[e]] * invS[row[e]];
  }
}

// ---- fallback path (ws too small / shape mismatch): global-atomic ----
__global__ void k_gemv_fb(const float* __restrict__ feat, const float* __restrict__ u2,
                          float* __restrict__ q, int N, int F) {
  const int lane = threadIdx.x & 63;
  const int wave = (blockIdx.x * blockDim.x + threadIdx.x) >> 6;
  if (wave >= N) return;
  const float* fr = feat + (size_t)wave * F;
  float a = 0.f;
  for (int i = lane; i < F; i += 64) a = fmaf(fr[i], u2[i], a);
  for (int off = 32; off; off >>= 1) a += __shfl_xor(a, off);
  if (lane == 0) q[wave] = a;
}
__global__ void k_scatter_B_at(const int* __restrict__ row, const int* __restrict__ col,
                               const float* __restrict__ v, const float* __restrict__ q,
                               float* __restrict__ B, int E) {
  int e = blockIdx.x * blockDim.x + threadIdx.x;
  if (e >= E) return;
  atomicAdd(&B[row[e]], v[e] * q[col[e]]);
}
__global__ void k_node_t(const float* __restrict__ B, float* __restrict__ t, int N) {
  int n = blockIdx.x * blockDim.x + threadIdx.x;
  if (n < N) t[n] = __expf(B[n]);
}
__global__ void k_scatter_S_at(const int* __restrict__ row, const int* __restrict__ col,
                               const float* __restrict__ t, float* __restrict__ S, int E) {
  int e = blockIdx.x * blockDim.x + threadIdx.x;
  if (e >= E) return;
  atomicAdd(&S[row[e]], t[col[e]]);
}
__global__ void k_out_div(const int* __restrict__ row, const int* __restrict__ col,
                          const float* __restrict__ vori, const float* __restrict__ t,
                          const float* __restrict__ S, float* __restrict__ out, int E) {
  int e = blockIdx.x * blockDim.x + threadIdx.x;
  if (e >= E) return;
  out[e] = vori[e] + t[col[e]] / S[row[e]];
}

extern "C" void kernel_launch(void* const* d_in, const int* in_sizes, int n_in,
                              void* d_out, int out_size, void* d_ws, size_t ws_size,
                              hipStream_t stream) {
  const float* vori = (const float*)d_in[0];
  const float* feat = (const float*)d_in[1];
  const int*   vind = (const int*)d_in[2];
  const float* W    = (const float*)d_in[4];
  const float* mw   = (const float*)d_in[6];

  const int E = in_sizes[0];
  const int H = in_sizes[6] / 2;        // 128
  const int F = in_sizes[4] / H;        // 512
  const int N = in_sizes[1] / F;        // 50000

  const int* row = vind;
  const int* col = vind + E;

  const int nb   = (N + RPB - 1) / RPB; // 391
  const int npad = nb * RPB;

  // ---- workspace: u2(F) q(N) t(npad) invS(npad) | cnt(nb*CPAD u32) |
  //      rec8(nb*CAP uint2)
  float* ws   = (float*)d_ws;
  float* u2   = ws;
  float* q    = u2 + F;
  float* t    = q + N;
  float* invS = t + npad;
  u32*   cnt  = (u32*)(invS + npad);
  size_t hdr  = (size_t)((char*)(cnt + (size_t)nb * CPAD) - (char*)d_ws);
  hdr = (hdr + 63) & ~(size_t)63;
  uint2* rec8 = (uint2*)((char*)d_ws + hdr);
  size_t need = hdr + (size_t)nb * CAP * sizeof(uint2);

  k_prep<<<(F + 255) / 256, 256, 0, stream>>>(W, mw, u2, cnt, F, H, nb * CPAD);

  if (ws_size >= need && F == 512 && H % 4 == 0 && nb <= NB_MAX) {
    k_fused<512><<<SB + GB, 1024, 0, stream>>>(row, col, vori, feat, u2, q,
                                               cnt, rec8, E, N, nb);
    k_sum_t<<<nb, 1024, 0, stream>>>(rec8, cnt, q, t);
    k_sum_invS<<<nb, 1024, 0, stream>>>(rec8, cnt, t, invS);
    const int e4 = (E + 3) / 4;
    k_out<<<(e4 + 255) / 256, 256, 0, stream>>>(row, col, vori, t, invS,
                                                (float*)d_out, E);
  } else {
    const int eb  = (E + 255) / 256;
    const int nbk = (N + 255) / 256;
    float* S = invS;
    k_gemv_fb<<<(N * 64 + 255) / 256, 256, 0, stream>>>(feat, u2, q, N, F);
    hipMemsetAsync((void*)S, 0, sizeof(float) * (size_t)npad, stream);
    k_scatter_B_at<<<eb, 256, 0, stream>>>(row, col, vori, q, S, E);
    k_node_t<<<nbk, 256, 0, stream>>>(S, t, N);
    hipMemsetAsync((void*)S, 0, sizeof(float) * (size_t)npad, stream);
    k_scatter_S_at<<<eb, 256, 0, stream>>>(row, col, t, S, E);
    k_out_div<<<eb, 256, 0, stream>>>(row, col, vori, t, S, (float*)d_out, E);
  }
}